// Round 1
// baseline (1354.834 us; speedup 1.0000x reference)
//
#include <hip/hip_runtime.h>
#include <float.h>

// Problem constants (from reference file)
#define N_ATOMS 2097152
#define D_FEAT  128
#define BATCH   16384

// One block (256 threads) per segment.
//   lane layout: f4 = tid & 31  -> which float4 of the 128-float row (32 quads)
//                r  = tid >> 5  -> row slot (8 rows in flight per iteration)
// Rows are contiguous per segment because membership is sorted.
__global__ __launch_bounds__(256)
void GraphGather_seg_meanmax(const float* __restrict__ A,
                             const int*   __restrict__ mem,
                             float*       __restrict__ out)
{
    const int seg = blockIdx.x;
    const int tid = threadIdx.x;
    const int f4  = tid & 31;
    const int r   = tid >> 5;

    // --- find [start, end) via binary search on sorted membership ---
    // (uniform across the block; probes hit L1/L2, ~42 loads total)
    int lo = 0, hi = N_ATOMS;
    while (lo < hi) {
        int mid = (lo + hi) >> 1;
        if (mem[mid] < seg) lo = mid + 1; else hi = mid;
    }
    const int start = lo;
    hi = N_ATOMS;
    while (lo < hi) {
        int mid = (lo + hi) >> 1;
        if (mem[mid] < seg + 1) lo = mid + 1; else hi = mid;
    }
    const int end = lo;

    // --- streaming accumulation: float4 loads, 8 rows per block-iteration ---
    const float4* __restrict__ A4 = reinterpret_cast<const float4*>(A);
    float4 s  = make_float4(0.f, 0.f, 0.f, 0.f);
    float4 mx = make_float4(-FLT_MAX, -FLT_MAX, -FLT_MAX, -FLT_MAX);

    for (int row = start + r; row < end; row += 8) {
        float4 v = A4[(size_t)row * 32 + f4];
        s.x += v.x; s.y += v.y; s.z += v.z; s.w += v.w;
        mx.x = fmaxf(mx.x, v.x);
        mx.y = fmaxf(mx.y, v.y);
        mx.z = fmaxf(mx.z, v.z);
        mx.w = fmaxf(mx.w, v.w);
    }

    // --- LDS tree reduction over the 8 row slots (stride-32 in tid) ---
    __shared__ float4 s_sum[256];
    __shared__ float4 s_max[256];
    s_sum[tid] = s;
    s_max[tid] = mx;
    __syncthreads();

    #pragma unroll
    for (int off = 128; off >= 32; off >>= 1) {
        if (tid < off) {
            float4 a = s_sum[tid], b = s_sum[tid + off];
            a.x += b.x; a.y += b.y; a.z += b.z; a.w += b.w;
            s_sum[tid] = a;
            float4 c = s_max[tid], d = s_max[tid + off];
            c.x = fmaxf(c.x, d.x); c.y = fmaxf(c.y, d.y);
            c.z = fmaxf(c.z, d.z); c.w = fmaxf(c.w, d.w);
            s_max[tid] = c;
        }
        __syncthreads();
    }

    // --- epilogue: lanes 0..31 write mean (first 128) and max (last 128) ---
    if (tid < 32) {
        const int cnt = end - start;
        const float inv = (cnt > 0) ? (1.0f / (float)cnt) : 0.0f;
        float4 sm = s_sum[tid];
        float4 mean = make_float4(sm.x * inv, sm.y * inv, sm.z * inv, sm.w * inv);
        float4 mm = s_max[tid];

        float4* o4 = reinterpret_cast<float4*>(out + (size_t)seg * (2 * D_FEAT));
        o4[f4]      = mean;  // mean block: cols [0,128)
        o4[32 + f4] = mm;    // max  block: cols [128,256)
    }
}

extern "C" void kernel_launch(void* const* d_in, const int* in_sizes, int n_in,
                              void* d_out, int out_size, void* d_ws, size_t ws_size,
                              hipStream_t stream) {
    const float* A   = (const float*)d_in[0];   // atom_features [N_ATOMS, 128] fp32
    const int*   mem = (const int*)d_in[1];     // membership [N_ATOMS] int32, sorted
    // d_in[2] = batch_size scalar; compile-time constant BATCH used instead.
    float* out = (float*)d_out;                  // [BATCH, 256] fp32

    GraphGather_seg_meanmax<<<BATCH, 256, 0, stream>>>(A, mem, out);
}